// Round 4
// baseline (346.346 us; speedup 1.0000x reference)
//
#include <hip/hip_runtime.h>
#include <math.h>

namespace {
constexpr int   BS_   = 64;
constexpr int   D_    = 768;
constexpr int   NVL_  = 192;            // 3*BS rows of vl_embeddings
constexpr int   NQ_   = 128;            // query rows (vl[64:])
constexpr int   CAP_  = 131072;
constexpr int   NCOL_ = NVL_ + CAP_;    // 131264 (the PRE dimension)
constexpr float THR_  = 0.5f;
constexpr float EPS_  = 1e-8f;

// workspace float offsets
constexpr int WS_QN   = 0;    // 128 query norms
constexpr int WS_SL   = 128;  // 1   global label sum
constexpr int WS_MN   = 160;  // 128 per-query min(sim_m)
constexpr int WS_MX   = 288;  // 128 per-query max(sim_m)
constexpr int WS_SS   = 416;  // 128 per-query sum(sim_m + 1)
constexpr int WS_SSL  = 544;  // 128 per-query sum((sim_m + 1)*label)
constexpr int WS_S0   = 672;  // 128 per-query sum(sim where selected)
constexpr int WS_CNT  = 800;  // 128 per-query count(selected)
constexpr int WS_ZERO = 1024; // 768 zero floats (safe OOB source)

constexpr int TM = 128;       // queue-rows (PRE dim) per block
}

using bf16x8 = __attribute__((ext_vector_type(8))) short;
using f32x4  = __attribute__((ext_vector_type(4))) float;

__device__ inline void atomicMinF(float* addr, float v) {
    if (v >= 0.f) atomicMin((int*)addr, __float_as_int(v));
    else          atomicMax((unsigned int*)addr, __float_as_uint(v));
}
__device__ inline void atomicMaxF(float* addr, float v) {
    if (v >= 0.f) atomicMax((int*)addr, __float_as_int(v));
    else          atomicMin((unsigned int*)addr, __float_as_uint(v));
}
// pack two f32 -> two bf16 (RNE) in one u32
__device__ inline unsigned pk2bf(float a, float b) {
    unsigned ua = __float_as_uint(a), ub = __float_as_uint(b);
    ua += 0x7fffu + ((ua >> 16) & 1u);
    ub += 0x7fffu + ((ub >> 16) & 1u);
    return (ua >> 16) | (ub & 0xffff0000u);
}

// ---------------- kernel 0: init accumulators + zero pad buffer ----------------
__global__ void lpe_init(float* ws) {
    int t = threadIdx.x;
    if (t < NQ_) {
        ws[WS_MN + t]  = INFINITY;
        ws[WS_MX + t]  = -INFINITY;
        ws[WS_SS + t]  = 0.f;
        ws[WS_SSL + t] = 0.f;
        ws[WS_S0 + t]  = 0.f;
        ws[WS_CNT + t] = 0.f;
    }
    if (t == 0) ws[WS_SL] = 0.f;
    for (int i = t; i < D_; i += 256) ws[WS_ZERO + i] = 0.f;
}

// ---------------- kernel 1: query norms + global label sum ----------------
__global__ void lpe_prep(const float* __restrict__ vl,
                         const float* __restrict__ itm,
                         const float* __restrict__ expl,
                         float* ws) {
    __shared__ float red[256];
    int b = blockIdx.x, t = threadIdx.x;
    if (b < NQ_) {
        const float* row = vl + (size_t)(BS_ + b) * D_;
        float s = 0.f;
        for (int k = t; k < D_; k += 256) { float v = row[k]; s += v * v; }
        red[t] = s; __syncthreads();
        for (int o = 128; o > 0; o >>= 1) { if (t < o) red[t] += red[t + o]; __syncthreads(); }
        if (t == 0) ws[WS_QN + b] = sqrtf(red[0]);
    } else {
        int idx = (b - NQ_) * 256 + t;
        float s = 0.f;
        for (int j = idx; j < NCOL_; j += 256 * 256)
            s += (j < NVL_) ? itm[j] : expl[j - NVL_];
        red[t] = s; __syncthreads();
        for (int o = 128; o > 0; o >>= 1) { if (t < o) red[t] += red[t + o]; __syncthreads(); }
        if (t == 0) atomicAdd(ws + WS_SL, red[0]);
    }
}

// ---------------- kernel 2: barrier-free streaming MFMA + stats ----------------
// M = queue/pre rows (tiled per block), N = 128 queries, K = 768.
__global__ __launch_bounds__(256, 3) void lpe_main(
        const float* __restrict__ vl, const float* __restrict__ score,
        const float* __restrict__ itm, const float* __restrict__ queue,
        const float* __restrict__ expl, const float* __restrict__ W,
        const float* __restrict__ bvec, float* ws) {
    __shared__ float rn_s[TM], rsc_s[TM], lab_s[TM];
    __shared__ float qn_sh[NQ_], qsc_sh[NQ_];
    __shared__ float qmn[NQ_], qmx[NQ_], qss[NQ_], qssl[NQ_], qs0[NQ_], qcnt[NQ_];

    const int t    = threadIdx.x;
    const int lane = t & 63;
    const int wv   = t >> 6;        // wave 0..3, owns 32 PRE rows
    const int fr   = lane & 15;
    const int fq   = lane >> 4;
    const int row0 = blockIdx.x * TM;

    if (t < NQ_) {
        qn_sh[t]  = ws[WS_QN + t];
        qsc_sh[t] = score[BS_ + t];
        qmn[t] = INFINITY; qmx[t] = -INFINITY;
        qss[t] = 0.f; qssl[t] = 0.f; qs0[t] = 0.f; qcnt[t] = 0.f;
        int rg = row0 + t;
        lab_s[t] = (rg < NCOL_) ? ((rg < NVL_) ? itm[rg] : expl[rg - NVL_]) : 0.f;
    }
    const float b0 = bvec[0], b1 = bvec[1];

    // per-lane A (pre-row) pointers; OOB rows -> zero buffer (exact)
    const float* zb = ws + WS_ZERO;
    const float* ap[2];
#pragma unroll
    for (int m = 0; m < 2; ++m) {
        int rg = row0 + wv * 32 + m * 16 + fr;
        const float* p = (rg < NVL_)  ? (vl + (size_t)rg * D_)
                       : (rg < NCOL_) ? (queue + (size_t)(rg - NVL_) * D_)
                                      : zb;
        ap[m] = p + fq * 8;
    }
    const float* qb = vl + (size_t)(BS_ + fr) * D_ + fq * 8;   // query rows (B operand)
    const float* wp = W + fq * 16;                             // W pairs for this lane's k

    float ssA[2] = {0.f, 0.f}, z0A[2] = {0.f, 0.f}, z1A[2] = {0.f, 0.f};
    f32x4 acc[2][8];
#pragma unroll
    for (int m = 0; m < 2; ++m)
#pragma unroll
        for (int n = 0; n < 8; ++n) acc[m][n] = (f32x4){0.f, 0.f, 0.f, 0.f};

#pragma unroll 2
    for (int kk = 0; kk < D_ / 32; ++kk) {
        const int ko = kk * 32;
        // W slice for this lane's 8 k's (L1-resident broadcast)
        const float4 w0 = *(const float4*)(wp + 2 * ko);
        const float4 w1 = *(const float4*)(wp + 2 * ko + 4);
        const float4 w2 = *(const float4*)(wp + 2 * ko + 8);
        const float4 w3 = *(const float4*)(wp + 2 * ko + 12);
        bf16x8 af[2];
#pragma unroll
        for (int m = 0; m < 2; ++m) {
            const float4 v0 = *(const float4*)(ap[m] + ko);
            const float4 v1 = *(const float4*)(ap[m] + ko + 4);
            ssA[m] += v0.x*v0.x + v0.y*v0.y + v0.z*v0.z + v0.w*v0.w
                    + v1.x*v1.x + v1.y*v1.y + v1.z*v1.z + v1.w*v1.w;
            z0A[m] += v0.x*w0.x + v0.y*w0.z + v0.z*w1.x + v0.w*w1.z
                    + v1.x*w2.x + v1.y*w2.z + v1.z*w3.x + v1.w*w3.z;
            z1A[m] += v0.x*w0.y + v0.y*w0.w + v0.z*w1.y + v0.w*w1.w
                    + v1.x*w2.y + v1.y*w2.w + v1.z*w3.y + v1.w*w3.w;
            union { unsigned u[4]; bf16x8 v; } cv;
            cv.u[0] = pk2bf(v0.x, v0.y); cv.u[1] = pk2bf(v0.z, v0.w);
            cv.u[2] = pk2bf(v1.x, v1.y); cv.u[3] = pk2bf(v1.z, v1.w);
            af[m] = cv.v;
        }
#pragma unroll
        for (int n = 0; n < 8; ++n) {
            const float* qp = qb + (size_t)n * 16 * D_ + ko;
            const float4 q0 = *(const float4*)qp;
            const float4 q1 = *(const float4*)(qp + 4);
            union { unsigned u[4]; bf16x8 v; } cv;
            cv.u[0] = pk2bf(q0.x, q0.y); cv.u[1] = pk2bf(q0.z, q0.w);
            cv.u[2] = pk2bf(q1.x, q1.y); cv.u[3] = pk2bf(q1.z, q1.w);
            acc[0][n] = __builtin_amdgcn_mfma_f32_16x16x32_bf16(af[0], cv.v, acc[0][n], 0, 0, 0);
            acc[1][n] = __builtin_amdgcn_mfma_f32_16x16x32_bf16(af[1], cv.v, acc[1][n], 0, 0, 0);
        }
    }

    // per-pre-row stats: reduce over the 4 fq lanes sharing row (lane bits 4,5)
#pragma unroll
    for (int m = 0; m < 2; ++m) {
        ssA[m] += __shfl_xor(ssA[m], 16); ssA[m] += __shfl_xor(ssA[m], 32);
        z0A[m] += __shfl_xor(z0A[m], 16); z0A[m] += __shfl_xor(z0A[m], 32);
        z1A[m] += __shfl_xor(z1A[m], 16); z1A[m] += __shfl_xor(z1A[m], 32);
        if (fq == 0) {
            const int r  = wv * 32 + m * 16 + fr;
            const int rg = row0 + r;
            rn_s[r] = sqrtf(ssA[m]);
            float sc;
            if (rg < NVL_) sc = score[rg];
            else { float z = (z1A[m] + b1) - (z0A[m] + b0); sc = 1.f / (1.f + expf(-z)); }
            rsc_s[r] = sc;
        }
    }
    __syncthreads();

    // epilogue: per-query online reductions over this block's TM pre-rows
#pragma unroll
    for (int n = 0; n < 8; ++n) {
        const int   c   = n * 16 + fr;
        const float qn  = qn_sh[c];
        const float qsc = qsc_sh[c];
        float mn = INFINITY, mx = -INFINITY, sss = 0.f, ssl = 0.f, s0 = 0.f, cnt = 0.f;
#pragma unroll
        for (int m = 0; m < 2; ++m) {
#pragma unroll
            for (int j = 0; j < 4; ++j) {
                const int r  = wv * 32 + m * 16 + fq * 4 + j;   // C row = pre row
                const int rg = row0 + r;
                const float d    = acc[m][n][j];
                const float cosv = d / fmaxf(rn_s[r] * qn, EPS_);
                float dd = rsc_s[r] - qsc; dd *= dd;
                const float sim   = cosv * (1.f - dd);
                const bool  sel   = (cosv >= THR_);
                const float sim_m = sel ? sim : -1.f;
                const bool  valid = (rg < NCOL_);
                mn = fminf(mn, valid ? sim_m : INFINITY);
                mx = fmaxf(mx, valid ? sim_m : -INFINITY);
                sss += sim_m + 1.f;                 // OOB rows: cos=0 -> exactly 0
                ssl += (sim_m + 1.f) * lab_s[r];
                if (sel) { s0 += sim; cnt += 1.f; }
            }
        }
        // combine the 4 fq lanes holding the same query c
        mn  = fminf(mn, __shfl_xor(mn, 16)); mn  = fminf(mn, __shfl_xor(mn, 32));
        mx  = fmaxf(mx, __shfl_xor(mx, 16)); mx  = fmaxf(mx, __shfl_xor(mx, 32));
        sss += __shfl_xor(sss, 16); sss += __shfl_xor(sss, 32);
        ssl += __shfl_xor(ssl, 16); ssl += __shfl_xor(ssl, 32);
        s0  += __shfl_xor(s0, 16);  s0  += __shfl_xor(s0, 32);
        cnt += __shfl_xor(cnt, 16); cnt += __shfl_xor(cnt, 32);
        if (fq == 0) {
            atomicMinF(&qmn[c], mn);
            atomicMaxF(&qmx[c], mx);
            atomicAdd(&qss[c],  sss);
            atomicAdd(&qssl[c], ssl);
            atomicAdd(&qs0[c],  s0);
            atomicAdd(&qcnt[c], cnt);
        }
    }
    __syncthreads();
    if (t < NQ_) {
        atomicMinF(ws + WS_MN + t, qmn[t]);
        atomicMaxF(ws + WS_MX + t, qmx[t]);
        atomicAdd(ws + WS_SS + t,  qss[t]);
        atomicAdd(ws + WS_SSL + t, qssl[t]);
        atomicAdd(ws + WS_S0 + t,  qs0[t]);
        atomicAdd(ws + WS_CNT + t, qcnt[t]);
    }
}

// ---------------- kernel 3: finalize outputs ----------------
__global__ void lpe_final(float* out, const float* ws) {
    int t = threadIdx.x;
    if (t < BS_) {
        out[t] = 1.f;            // exp_itm_label[:64]
        out[192 + t] = 1.f;      // exp_wo_alter_label[:64]
        out[385 + t] = 0.f;      // weights[:64]
    }
    if (t == 0) out[384] = 1.0f; // gamma = 131264/131264
    if (t >= BS_ && t < NVL_) {
        int i = t - BS_;
        float mn   = ws[WS_MN + i],  mx   = ws[WS_MX + i];
        float ssP  = ws[WS_SS + i],  sslP = ws[WS_SSL + i];
        float s0   = ws[WS_S0 + i],  cnt  = ws[WS_CNT + i];
        float Sl   = ws[WS_SL];
        float denomA = mx - mn + 1e-8f;
        float shift  = mn + 1.f;            // == 0 when min is the -1 sentinel
        float sumd = (ssP - (float)NCOL_ * shift) / denomA;
        float num  = (sslP - shift * Sl) / denomA;
        float wo   = num / (sumd + 1e-8f);
        float alt  = fmaxf(wo, 0.f);
        float w    = (cnt != 0.f) ? s0 / fmaxf(cnt, 1.f) : 0.f;
        float wt   = fmaxf(w - THR_, 0.f) / (1.f - THR_);
        out[BS_ + i] = alt;          // exp_itm_label[64:]
        out[192 + BS_ + i] = wo;     // exp_wo_alter_label[64:]
        out[385 + BS_ + i] = wt;     // weights[64:]
    }
}

extern "C" void kernel_launch(void* const* d_in, const int* in_sizes, int n_in,
                              void* d_out, int out_size, void* d_ws, size_t ws_size,
                              hipStream_t stream) {
    const float* vl    = (const float*)d_in[0];
    const float* score = (const float*)d_in[1];
    const float* itm   = (const float*)d_in[2];
    const float* queue = (const float*)d_in[3];
    const float* expl  = (const float*)d_in[4];
    const float* W     = (const float*)d_in[5];
    const float* b     = (const float*)d_in[6];
    float* out = (float*)d_out;
    float* ws  = (float*)d_ws;

    lpe_init<<<1, 256, 0, stream>>>(ws);
    lpe_prep<<<NQ_ + 256, 256, 0, stream>>>(vl, itm, expl, ws);
    const int nblk = (NCOL_ + TM - 1) / TM;   // 1026
    lpe_main<<<nblk, 256, 0, stream>>>(vl, score, itm, queue, expl, W, b, ws);
    lpe_final<<<1, 256, 0, stream>>>(out, ws);
}

// Round 5
// 293.697 us; speedup vs baseline: 1.1793x; 1.1793x over previous
//
#include <hip/hip_runtime.h>
#include <math.h>

namespace {
constexpr int   BS_   = 64;
constexpr int   D_    = 768;
constexpr int   NVL_  = 192;            // 3*BS rows of vl_embeddings
constexpr int   NQ_   = 128;            // query rows (vl[64:])
constexpr int   CAP_  = 131072;
constexpr int   NCOL_ = NVL_ + CAP_;    // 131264 (the PRE dimension)
constexpr float THR_  = 0.5f;
constexpr float EPS_  = 1e-8f;

// workspace float offsets
constexpr int WS_QN   = 0;    // 128 query norms
constexpr int WS_SL   = 128;  // 1   global label sum
constexpr int WS_MN   = 160;  // 128 per-query min(sim_m)
constexpr int WS_MX   = 288;  // 128 per-query max(sim_m)
constexpr int WS_SS   = 416;  // 128 per-query sum(sim_m + 1)
constexpr int WS_SSL  = 544;  // 128 per-query sum((sim_m + 1)*label)
constexpr int WS_S0   = 672;  // 128 per-query sum(sim where selected)
constexpr int WS_CNT  = 800;  // 128 per-query count(selected)
constexpr int WS_ZERO = 1024; // 768 zero floats (safe OOB source)

constexpr int TM     = 128;            // pre-rows per block
constexpr int BK     = 64;             // fp32 k per step
constexpr int NSTEP  = D_ / BK;        // 12
constexpr int TILE_B = TM * BK * 4;    // 32768 B per LDS buffer
}

using bf16x8 = __attribute__((ext_vector_type(8))) short;
using f32x4  = __attribute__((ext_vector_type(4))) float;

__device__ inline void atomicMinF(float* addr, float v) {
    if (v >= 0.f) atomicMin((int*)addr, __float_as_int(v));
    else          atomicMax((unsigned int*)addr, __float_as_uint(v));
}
__device__ inline void atomicMaxF(float* addr, float v) {
    if (v >= 0.f) atomicMax((int*)addr, __float_as_int(v));
    else          atomicMin((unsigned int*)addr, __float_as_uint(v));
}
// pack two f32 -> two bf16 (RNE) in one u32
__device__ inline unsigned pk2bf(float a, float b) {
    unsigned ua = __float_as_uint(a), ub = __float_as_uint(b);
    ua += 0x7fffu + ((ua >> 16) & 1u);
    ub += 0x7fffu + ((ub >> 16) & 1u);
    return (ua >> 16) | (ub & 0xffff0000u);
}

// ---------------- kernel 0: init accumulators + zero pad buffer ----------------
__global__ void lpe_init(float* ws) {
    int t = threadIdx.x;
    if (t < NQ_) {
        ws[WS_MN + t]  = INFINITY;
        ws[WS_MX + t]  = -INFINITY;
        ws[WS_SS + t]  = 0.f;
        ws[WS_SSL + t] = 0.f;
        ws[WS_S0 + t]  = 0.f;
        ws[WS_CNT + t] = 0.f;
    }
    if (t == 0) ws[WS_SL] = 0.f;
    for (int i = t; i < D_; i += 256) ws[WS_ZERO + i] = 0.f;
}

// ---------------- kernel 1: query norms + global label sum ----------------
__global__ void lpe_prep(const float* __restrict__ vl,
                         const float* __restrict__ itm,
                         const float* __restrict__ expl,
                         float* ws) {
    __shared__ float red[256];
    int b = blockIdx.x, t = threadIdx.x;
    if (b < NQ_) {
        const float* row = vl + (size_t)(BS_ + b) * D_;
        float s = 0.f;
        for (int k = t; k < D_; k += 256) { float v = row[k]; s += v * v; }
        red[t] = s; __syncthreads();
        for (int o = 128; o > 0; o >>= 1) { if (t < o) red[t] += red[t + o]; __syncthreads(); }
        if (t == 0) ws[WS_QN + b] = sqrtf(red[0]);
    } else {
        int idx = (b - NQ_) * 256 + t;
        float s = 0.f;
        for (int j = idx; j < NCOL_; j += 256 * 256)
            s += (j < NVL_) ? itm[j] : expl[j - NVL_];
        red[t] = s; __syncthreads();
        for (int o = 128; o > 0; o >>= 1) { if (t < o) red[t] += red[t + o]; __syncthreads(); }
        if (t == 0) atomicAdd(ws + WS_SL, red[0]);
    }
}

// ---------------- kernel 2: 2-phase pipelined gload_lds MFMA + stats ----------------
// M = pre rows (tiled per block), N = 128 queries, K = 768.
// A tile staged fp32 via global_load_lds, double-buffered, source-swizzled.
__global__ __launch_bounds__(256, 2) void lpe_main(
        const float* __restrict__ vl, const float* __restrict__ score,
        const float* __restrict__ itm, const float* __restrict__ queue,
        const float* __restrict__ expl, const float* __restrict__ W,
        const float* __restrict__ bvec, float* ws) {
    __shared__ float As[2 * TM * BK];   // 64 KB fp32, swizzled within 256B rows
    __shared__ float rn_s[TM], rsc_s[TM], lab_s[TM];
    __shared__ float qn_sh[NQ_], qsc_sh[NQ_];
    __shared__ float qmn[NQ_], qmx[NQ_], qss[NQ_], qssl[NQ_], qs0[NQ_], qcnt[NQ_];

    const int t    = threadIdx.x;
    const int lane = t & 63;
    const int wv   = t >> 6;        // wave 0..3, computes 32 pre-rows
    const int fr   = lane & 15;
    const int fq   = lane >> 4;
    const int row0 = blockIdx.x * TM;

    if (t < NQ_) {
        qn_sh[t]  = ws[WS_QN + t];
        qsc_sh[t] = score[BS_ + t];
        qmn[t] = INFINITY; qmx[t] = -INFINITY;
        qss[t] = 0.f; qssl[t] = 0.f; qs0[t] = 0.f; qcnt[t] = 0.f;
        int rg = row0 + t;
        lab_s[t] = (rg < NCOL_) ? ((rg < NVL_) ? itm[rg] : expl[rg - NVL_]) : 0.f;
    }
    const float b0 = bvec[0], b1 = bvec[1];
    const float* zb = ws + WS_ZERO;

    // ---- staging source pointers (8 issues/thread; wave i-th issue covers
    //      LDS rows wv*4 + i*16 .. +3, lane supplies 16B at swizzled offset)
    const char* sp[8];
#pragma unroll
    for (int i = 0; i < 8; ++i) {
        const int r  = wv * 4 + i * 16 + fq;     // LDS row (= lane>>4 within group)
        const int rg = row0 + r;
        const float* base = (rg < NVL_)  ? (vl + (size_t)rg * D_)
                          : (rg < NCOL_) ? (queue + (size_t)(rg - NVL_) * D_)
                                         : zb;
        const int wro = (fr << 4) ^ ((r & 7) << 4);   // pre-swizzled source offset
        sp[i] = (const char*)base + wro;
    }

    f32x4 acc[2][8];
#pragma unroll
    for (int m = 0; m < 2; ++m)
#pragma unroll
        for (int n = 0; n < 8; ++n) acc[m][n] = (f32x4){0.f, 0.f, 0.f, 0.f};
    float ssA[2] = {0.f, 0.f}, z0A[2] = {0.f, 0.f}, z1A[2] = {0.f, 0.f};

#define STAGE(buf, s)                                                          \
    {                                                                          \
        char* lb = (char*)As + (buf) * TILE_B + wv * 1024;                     \
        const int koff = (s) * (BK * 4);                                       \
        _Pragma("unroll")                                                      \
        for (int i = 0; i < 8; ++i) {                                          \
            __builtin_amdgcn_global_load_lds(                                  \
                (const __attribute__((address_space(1))) void*)(sp[i] + koff), \
                (__attribute__((address_space(3))) void*)(lb + i * 4096),      \
                16, 0, 0);                                                     \
        }                                                                      \
    }

    STAGE(0, 0);
    __syncthreads();

    int cur = 0;
    for (int s = 0; s < NSTEP; ++s) {
        if (s + 1 < NSTEP) STAGE(cur ^ 1, s + 1);       // prefetch next tile
        const char* Ab = (const char*)As + cur * TILE_B;
#pragma unroll
        for (int kks = 0; kks < 2; ++kks) {
            const int kg = s * 64 + kks * 32 + fq * 8;  // this lane's global k base
            const float4 w0 = *(const float4*)(W + 2 * kg);
            const float4 w1 = *(const float4*)(W + 2 * kg + 4);
            const float4 w2 = *(const float4*)(W + 2 * kg + 8);
            const float4 w3 = *(const float4*)(W + 2 * kg + 12);
            bf16x8 af[2];
#pragma unroll
            for (int m = 0; m < 2; ++m) {
                const int r   = wv * 32 + m * 16 + fr;
                const int sw  = (r & 7) << 4;
                const int lin = kks * 128 + fq * 32;
                const float4 v0 = *(const float4*)(Ab + (size_t)r * 256 + (lin ^ sw));
                const float4 v1 = *(const float4*)(Ab + (size_t)r * 256 + ((lin + 16) ^ sw));
                ssA[m] += v0.x*v0.x + v0.y*v0.y + v0.z*v0.z + v0.w*v0.w
                        + v1.x*v1.x + v1.y*v1.y + v1.z*v1.z + v1.w*v1.w;
                z0A[m] += v0.x*w0.x + v0.y*w0.z + v0.z*w1.x + v0.w*w1.z
                        + v1.x*w2.x + v1.y*w2.z + v1.z*w3.x + v1.w*w3.z;
                z1A[m] += v0.x*w0.y + v0.y*w0.w + v0.z*w1.y + v0.w*w1.w
                        + v1.x*w2.y + v1.y*w2.w + v1.z*w3.y + v1.w*w3.w;
                union { unsigned u[4]; bf16x8 v; } cv;
                cv.u[0] = pk2bf(v0.x, v0.y); cv.u[1] = pk2bf(v0.z, v0.w);
                cv.u[2] = pk2bf(v1.x, v1.y); cv.u[3] = pk2bf(v1.z, v1.w);
                af[m] = cv.v;
            }
#pragma unroll
            for (int n = 0; n < 8; ++n) {
                const float* qp = vl + (size_t)(BS_ + n * 16 + fr) * D_
                                + s * 64 + kks * 32 + fq * 8;
                const float4 q0 = *(const float4*)qp;
                const float4 q1 = *(const float4*)(qp + 4);
                union { unsigned u[4]; bf16x8 v; } cv;
                cv.u[0] = pk2bf(q0.x, q0.y); cv.u[1] = pk2bf(q0.z, q0.w);
                cv.u[2] = pk2bf(q1.x, q1.y); cv.u[3] = pk2bf(q1.z, q1.w);
                acc[0][n] = __builtin_amdgcn_mfma_f32_16x16x32_bf16(af[0], cv.v, acc[0][n], 0, 0, 0);
                acc[1][n] = __builtin_amdgcn_mfma_f32_16x16x32_bf16(af[1], cv.v, acc[1][n], 0, 0, 0);
            }
        }
        __syncthreads();          // drains prefetch vmcnt; next tile ready
        cur ^= 1;
    }
#undef STAGE

    // per-pre-row stats: reduce over the 4 fq lanes sharing a row
#pragma unroll
    for (int m = 0; m < 2; ++m) {
        ssA[m] += __shfl_xor(ssA[m], 16); ssA[m] += __shfl_xor(ssA[m], 32);
        z0A[m] += __shfl_xor(z0A[m], 16); z0A[m] += __shfl_xor(z0A[m], 32);
        z1A[m] += __shfl_xor(z1A[m], 16); z1A[m] += __shfl_xor(z1A[m], 32);
        if (fq == 0) {
            const int r  = wv * 32 + m * 16 + fr;
            const int rg = row0 + r;
            rn_s[r] = sqrtf(ssA[m]);
            float sc;
            if (rg < NVL_) sc = score[rg];
            else { float z = (z1A[m] + b1) - (z0A[m] + b0); sc = 1.f / (1.f + expf(-z)); }
            rsc_s[r] = sc;
        }
    }
    __syncthreads();

    // epilogue: per-query online reductions over this block's TM pre-rows
#pragma unroll
    for (int n = 0; n < 8; ++n) {
        const int   c   = n * 16 + fr;
        const float qn  = qn_sh[c];
        const float qsc = qsc_sh[c];
        float mn = INFINITY, mx = -INFINITY, sss = 0.f, ssl = 0.f, s0 = 0.f, cnt = 0.f;
#pragma unroll
        for (int m = 0; m < 2; ++m) {
#pragma unroll
            for (int j = 0; j < 4; ++j) {
                const int r  = wv * 32 + m * 16 + fq * 4 + j;   // C row = pre row
                const int rg = row0 + r;
                const float d    = acc[m][n][j];
                const float cosv = d / fmaxf(rn_s[r] * qn, EPS_);
                float dd = rsc_s[r] - qsc; dd *= dd;
                const float sim   = cosv * (1.f - dd);
                const bool  sel   = (cosv >= THR_);
                const float sim_m = sel ? sim : -1.f;
                const bool  valid = (rg < NCOL_);
                mn = fminf(mn, valid ? sim_m : INFINITY);
                mx = fmaxf(mx, valid ? sim_m : -INFINITY);
                sss += sim_m + 1.f;                 // OOB rows: cos=0 -> exactly 0
                ssl += (sim_m + 1.f) * lab_s[r];
                if (sel) { s0 += sim; cnt += 1.f; }
            }
        }
        mn  = fminf(mn, __shfl_xor(mn, 16)); mn  = fminf(mn, __shfl_xor(mn, 32));
        mx  = fmaxf(mx, __shfl_xor(mx, 16)); mx  = fmaxf(mx, __shfl_xor(mx, 32));
        sss += __shfl_xor(sss, 16); sss += __shfl_xor(sss, 32);
        ssl += __shfl_xor(ssl, 16); ssl += __shfl_xor(ssl, 32);
        s0  += __shfl_xor(s0, 16);  s0  += __shfl_xor(s0, 32);
        cnt += __shfl_xor(cnt, 16); cnt += __shfl_xor(cnt, 32);
        if (fq == 0) {
            atomicMinF(&qmn[c], mn);
            atomicMaxF(&qmx[c], mx);
            atomicAdd(&qss[c],  sss);
            atomicAdd(&qssl[c], ssl);
            atomicAdd(&qs0[c],  s0);
            atomicAdd(&qcnt[c], cnt);
        }
    }
    __syncthreads();
    if (t < NQ_) {
        atomicMinF(ws + WS_MN + t, qmn[t]);
        atomicMaxF(ws + WS_MX + t, qmx[t]);
        atomicAdd(ws + WS_SS + t,  qss[t]);
        atomicAdd(ws + WS_SSL + t, qssl[t]);
        atomicAdd(ws + WS_S0 + t,  qs0[t]);
        atomicAdd(ws + WS_CNT + t, qcnt[t]);
    }
}

// ---------------- kernel 3: finalize outputs ----------------
__global__ void lpe_final(float* out, const float* ws) {
    int t = threadIdx.x;
    if (t < BS_) {
        out[t] = 1.f;            // exp_itm_label[:64]
        out[192 + t] = 1.f;      // exp_wo_alter_label[:64]
        out[385 + t] = 0.f;      // weights[:64]
    }
    if (t == 0) out[384] = 1.0f; // gamma = 131264/131264
    if (t >= BS_ && t < NVL_) {
        int i = t - BS_;
        float mn   = ws[WS_MN + i],  mx   = ws[WS_MX + i];
        float ssP  = ws[WS_SS + i],  sslP = ws[WS_SSL + i];
        float s0   = ws[WS_S0 + i],  cnt  = ws[WS_CNT + i];
        float Sl   = ws[WS_SL];
        float denomA = mx - mn + 1e-8f;
        float shift  = mn + 1.f;            // == 0 when min is the -1 sentinel
        float sumd = (ssP - (float)NCOL_ * shift) / denomA;
        float num  = (sslP - shift * Sl) / denomA;
        float wo   = num / (sumd + 1e-8f);
        float alt  = fmaxf(wo, 0.f);
        float w    = (cnt != 0.f) ? s0 / fmaxf(cnt, 1.f) : 0.f;
        float wt   = fmaxf(w - THR_, 0.f) / (1.f - THR_);
        out[BS_ + i] = alt;          // exp_itm_label[64:]
        out[192 + BS_ + i] = wo;     // exp_wo_alter_label[64:]
        out[385 + BS_ + i] = wt;     // weights[64:]
    }
}

extern "C" void kernel_launch(void* const* d_in, const int* in_sizes, int n_in,
                              void* d_out, int out_size, void* d_ws, size_t ws_size,
                              hipStream_t stream) {
    const float* vl    = (const float*)d_in[0];
    const float* score = (const float*)d_in[1];
    const float* itm   = (const float*)d_in[2];
    const float* queue = (const float*)d_in[3];
    const float* expl  = (const float*)d_in[4];
    const float* W     = (const float*)d_in[5];
    const float* b     = (const float*)d_in[6];
    float* out = (float*)d_out;
    float* ws  = (float*)d_ws;

    lpe_init<<<1, 256, 0, stream>>>(ws);
    lpe_prep<<<NQ_ + 256, 256, 0, stream>>>(vl, itm, expl, ws);
    const int nblk = (NCOL_ + TM - 1) / TM;   // 1026
    lpe_main<<<nblk, 256, 0, stream>>>(vl, score, itm, queue, expl, W, b, ws);
    lpe_final<<<1, 256, 0, stream>>>(out, ws);
}

// Round 6
// 191.225 us; speedup vs baseline: 1.8112x; 1.5359x over previous
//
#include <hip/hip_runtime.h>
#include <math.h>

namespace {
constexpr int   BS_   = 64;
constexpr int   D_    = 768;
constexpr int   NVL_  = 192;            // 3*BS rows of vl_embeddings
constexpr int   NQ_   = 128;            // query rows (vl[64:])
constexpr int   CAP_  = 131072;
constexpr int   NCOL_ = NVL_ + CAP_;    // 131264 (the PRE dimension)
constexpr float THR_  = 0.5f;
constexpr float EPS_  = 1e-8f;

// workspace float offsets
constexpr int WS_QN   = 0;    // 128 query norms
constexpr int WS_SL   = 128;  // 1   global label sum
constexpr int WS_MN   = 160;  // 128 per-query min(sim_m)
constexpr int WS_MX   = 288;  // 128 per-query max(sim_m)
constexpr int WS_SS   = 416;  // 128 per-query sum(sim_m + 1)
constexpr int WS_SSL  = 544;  // 128 per-query sum((sim_m + 1)*label)
constexpr int WS_S0   = 672;  // 128 per-query sum(sim where selected)
constexpr int WS_CNT  = 800;  // 128 per-query count(selected)
constexpr int WS_ZERO = 1024; // 768 zero floats (safe OOB source)
constexpr int WS_QBF  = 2048; // 49152 floats: q bf16, 24 tiles of 8192 B (swizzled LDS image)

constexpr int TM    = 128;    // pre-rows per block
constexpr int BK    = 32;     // k per step
constexpr int NSTEP = D_ / BK;   // 24
}

using bf16x8 = __attribute__((ext_vector_type(8))) short;
using f32x4  = __attribute__((ext_vector_type(4))) float;

__device__ inline void atomicMinF(float* addr, float v) {
    if (v >= 0.f) atomicMin((int*)addr, __float_as_int(v));
    else          atomicMax((unsigned int*)addr, __float_as_uint(v));
}
__device__ inline void atomicMaxF(float* addr, float v) {
    if (v >= 0.f) atomicMax((int*)addr, __float_as_int(v));
    else          atomicMin((unsigned int*)addr, __float_as_uint(v));
}
// pack two f32 -> two bf16 (RNE) in one u32
__device__ inline unsigned pk2bf(float a, float b) {
    unsigned ua = __float_as_uint(a), ub = __float_as_uint(b);
    ua += 0x7fffu + ((ua >> 16) & 1u);
    ub += 0x7fffu + ((ub >> 16) & 1u);
    return (ua >> 16) | (ub & 0xffff0000u);
}

// ---------------- kernel 0: init accumulators + zero pad buffer ----------------
__global__ void lpe_init(float* ws) {
    int t = threadIdx.x;
    if (t < NQ_) {
        ws[WS_MN + t]  = INFINITY;
        ws[WS_MX + t]  = -INFINITY;
        ws[WS_SS + t]  = 0.f;
        ws[WS_SSL + t] = 0.f;
        ws[WS_S0 + t]  = 0.f;
        ws[WS_CNT + t] = 0.f;
    }
    if (t == 0) ws[WS_SL] = 0.f;
    for (int i = t; i < D_; i += 256) ws[WS_ZERO + i] = 0.f;
}

// ---------------- kernel 1: query norms + q bf16 image + global label sum ----------------
__global__ void lpe_prep(const float* __restrict__ vl,
                         const float* __restrict__ itm,
                         const float* __restrict__ expl,
                         float* ws) {
    __shared__ float red[256];
    int b = blockIdx.x, t = threadIdx.x;
    if (b < NQ_) {
        const float* row = vl + (size_t)(BS_ + b) * D_;
        float s = 0.f;
        for (int k = t; k < D_; k += 256) { float v = row[k]; s += v * v; }
        red[t] = s; __syncthreads();
        for (int o = 128; o > 0; o >>= 1) { if (t < o) red[t] += red[t + o]; __syncthreads(); }
        if (t == 0) ws[WS_QN + b] = sqrtf(red[0]);
        // write swizzled bf16 image of this query row: tile s (8192 B) holds
        // [row][64B] with byte_off = (kk*2) ^ ((row>>1 & 3)<<4)
        unsigned* qbf = (unsigned*)(ws + WS_QBF);
        const int sw = ((b >> 1) & 3) << 4;
        for (int k2 = t; k2 < 384; k2 += 256) {
            const int k = 2 * k2, tile = k >> 5, kk = k & 31;
            const unsigned val = pk2bf(row[k], row[k + 1]);
            const int byte = tile * 8192 + b * 64 + (((kk * 2) ^ sw) & 63);
            qbf[byte >> 2] = val;
        }
    } else {
        int idx = (b - NQ_) * 256 + t;
        float s = 0.f;
        for (int j = idx; j < NCOL_; j += 256 * 256)
            s += (j < NVL_) ? itm[j] : expl[j - NVL_];
        red[t] = s; __syncthreads();
        for (int o = 128; o > 0; o >>= 1) { if (t < o) red[t] += red[t + o]; __syncthreads(); }
        if (t == 0) atomicAdd(ws + WS_SL, red[0]);
    }
}

// ---------------- kernel 2: m97-style bf16 GEMM, reg-staged A + gload_lds B ----------------
// M = pre rows (128/block), N = 128 queries, K = 768, BK = 32, dbuf, 1 barrier/step.
__global__ __launch_bounds__(256, 3) void lpe_main(
        const float* __restrict__ vl, const float* __restrict__ score,
        const float* __restrict__ itm, const float* __restrict__ queue,
        const float* __restrict__ expl, const float* __restrict__ W,
        const float* __restrict__ bvec, float* ws) {
    __shared__ short As[2][TM][BK];     // bf16, swizzled rows of 64 B
    __shared__ short Bs2[2][NQ_][BK];   // bf16 queries, same layout
    __shared__ float rn_s[TM], rsc_s[TM], lab_s[TM];
    __shared__ float qn_sh[NQ_], qsc_sh[NQ_];
    __shared__ float qmn[NQ_], qmx[NQ_], qss[NQ_], qssl[NQ_], qs0[NQ_], qcnt[NQ_];

    const int t    = threadIdx.x;
    const int lane = t & 63;
    const int wv   = t >> 6;        // wave 0..3 computes rows wv*32..+31
    const int fr   = lane & 15;
    const int fq   = lane >> 4;
    const int row0 = blockIdx.x * TM;

    if (t < NQ_) {
        qn_sh[t]  = ws[WS_QN + t];
        qsc_sh[t] = score[BS_ + t];
        qmn[t] = INFINITY; qmx[t] = -INFINITY;
        qss[t] = 0.f; qssl[t] = 0.f; qs0[t] = 0.f; qcnt[t] = 0.f;
        int rg = row0 + t;
        lab_s[t] = (rg < NCOL_) ? ((rg < NVL_) ? itm[rg] : expl[rg - NVL_]) : 0.f;
    }
    const float b0 = bvec[0], b1 = bvec[1];
    const float* zb = ws + WS_ZERO;

    // A staging: thread covers row r_st = t>>1, k-half kh (16 floats/step)
    const int r_st  = t >> 1;
    const int kh    = (t & 1) * 16;
    const int rg_st = row0 + r_st;
    const float* abase = (rg_st < NVL_)  ? (vl + (size_t)rg_st * D_)
                       : (rg_st < NCOL_) ? (queue + (size_t)(rg_st - NVL_) * D_)
                                         : zb;
    const float* aptr = abase + kh;
    const int asw   = ((r_st >> 1) & 3) << 4;
    const int aoff0 = (kh * 2) ^ asw;
    const int aoff1 = (kh * 2 + 16) ^ asw;

    const char* qbf     = (const char*)(ws + WS_QBF);
    const int  bsrc_off = wv * 1024 + lane * 16;

    float ss = 0.f, z0 = 0.f, z1 = 0.f;
    f32x4 acc[2][8];
#pragma unroll
    for (int m = 0; m < 2; ++m)
#pragma unroll
        for (int n = 0; n < 8; ++n) acc[m][n] = (f32x4){0.f, 0.f, 0.f, 0.f};

    float4 rgA[4], rgB[4];

#define LOAD_A(RG, S) {                                                        \
    const float* p_ = aptr + (S) * BK;                                         \
    RG[0] = *(const float4*)(p_);      RG[1] = *(const float4*)(p_ + 4);       \
    RG[2] = *(const float4*)(p_ + 8);  RG[3] = *(const float4*)(p_ + 12); }

#define STAGE_B(BUF, S) {                                                      \
    char* lb_ = (char*)&Bs2[BUF][0][0];                                        \
    _Pragma("unroll")                                                          \
    for (int i_ = 0; i_ < 2; ++i_)                                             \
        __builtin_amdgcn_global_load_lds(                                      \
            (const __attribute__((address_space(1))) void*)                    \
                (qbf + (S) * 8192 + i_ * 4096 + bsrc_off),                     \
            (__attribute__((address_space(3))) void*)(lb_ + wv * 1024 + i_ * 4096), \
            16, 0, 0); }

#define STATS_WRITE_A(RG, BUF, S) {                                            \
    const float* wp_ = W + 2 * ((S) * BK + kh);                                \
    _Pragma("unroll")                                                          \
    for (int i_ = 0; i_ < 4; ++i_) {                                           \
        const float4 v_  = RG[i_];                                             \
        const float4 wa_ = *(const float4*)(wp_ + 8 * i_);                     \
        const float4 wb_ = *(const float4*)(wp_ + 8 * i_ + 4);                 \
        ss += v_.x * v_.x + v_.y * v_.y + v_.z * v_.z + v_.w * v_.w;           \
        z0 += v_.x * wa_.x + v_.y * wa_.z + v_.z * wb_.x + v_.w * wb_.z;       \
        z1 += v_.x * wa_.y + v_.y * wa_.w + v_.z * wb_.y + v_.w * wb_.w;       \
    }                                                                          \
    union { unsigned u[4]; uint4 q; } c0_, c1_;                                \
    c0_.u[0] = pk2bf(RG[0].x, RG[0].y); c0_.u[1] = pk2bf(RG[0].z, RG[0].w);    \
    c0_.u[2] = pk2bf(RG[1].x, RG[1].y); c0_.u[3] = pk2bf(RG[1].z, RG[1].w);    \
    c1_.u[0] = pk2bf(RG[2].x, RG[2].y); c1_.u[1] = pk2bf(RG[2].z, RG[2].w);    \
    c1_.u[2] = pk2bf(RG[3].x, RG[3].y); c1_.u[3] = pk2bf(RG[3].z, RG[3].w);    \
    char* ab_ = (char*)&As[BUF][r_st][0];                                      \
    *(uint4*)(ab_ + aoff0) = c0_.q;                                            \
    *(uint4*)(ab_ + aoff1) = c1_.q; }

#define COMPUTE(BUF) {                                                         \
    const char* ab_ = (const char*)&As[BUF][0][0];                             \
    const char* bb_ = (const char*)&Bs2[BUF][0][0];                            \
    const int ra0_ = wv * 32 + fr, ra1_ = ra0_ + 16;                           \
    bf16x8 a0_ = *(const bf16x8*)(ab_ + ra0_ * 64 + 16 * (fq ^ ((ra0_ >> 1) & 3))); \
    bf16x8 a1_ = *(const bf16x8*)(ab_ + ra1_ * 64 + 16 * (fq ^ ((ra1_ >> 1) & 3))); \
    _Pragma("unroll")                                                          \
    for (int n_ = 0; n_ < 8; ++n_) {                                           \
        const int rb_ = n_ * 16 + fr;                                          \
        bf16x8 bv_ = *(const bf16x8*)(bb_ + rb_ * 64 + 16 * (fq ^ ((rb_ >> 1) & 3))); \
        acc[0][n_] = __builtin_amdgcn_mfma_f32_16x16x32_bf16(a0_, bv_, acc[0][n_], 0, 0, 0); \
        acc[1][n_] = __builtin_amdgcn_mfma_f32_16x16x32_bf16(a1_, bv_, acc[1][n_], 0, 0, 0); \
    } }

    // prologue: fill buffer 0
    LOAD_A(rgA, 0);
    STAGE_B(0, 0);
    STATS_WRITE_A(rgA, 0, 0);
    __syncthreads();

#pragma unroll 1
    for (int s2 = 0; s2 < NSTEP; s2 += 2) {
        LOAD_A(rgB, s2 + 1);
        STAGE_B(1, s2 + 1);
        COMPUTE(0);
        STATS_WRITE_A(rgB, 1, s2 + 1);
        __syncthreads();
        if (s2 + 2 < NSTEP) { LOAD_A(rgA, s2 + 2); STAGE_B(0, s2 + 2); }
        COMPUTE(1);
        if (s2 + 2 < NSTEP) STATS_WRITE_A(rgA, 0, s2 + 2);
        __syncthreads();
    }
#undef LOAD_A
#undef STAGE_B
#undef STATS_WRITE_A
#undef COMPUTE

    // finalize per-pre-row stats (pair t, t^1 holds the two k-halves)
    ss += __shfl_xor(ss, 1);
    z0 += __shfl_xor(z0, 1);
    z1 += __shfl_xor(z1, 1);
    if ((t & 1) == 0) {
        rn_s[r_st] = sqrtf(ss);
        float sc;
        if (rg_st < NVL_) sc = score[rg_st];
        else { float z = (z1 + b1) - (z0 + b0); sc = 1.f / (1.f + expf(-z)); }
        rsc_s[r_st] = sc;
    }
    __syncthreads();

    // epilogue: per-query online reductions over this block's TM pre-rows
#pragma unroll
    for (int n = 0; n < 8; ++n) {
        const int   c   = n * 16 + fr;
        const float qn  = qn_sh[c];
        const float qsc = qsc_sh[c];
        float mn = INFINITY, mx = -INFINITY, sss = 0.f, ssl = 0.f, s0 = 0.f, cnt = 0.f;
#pragma unroll
        for (int m = 0; m < 2; ++m) {
#pragma unroll
            for (int j = 0; j < 4; ++j) {
                const int r  = wv * 32 + m * 16 + fq * 4 + j;   // C row = pre row
                const int rg = row0 + r;
                const float d    = acc[m][n][j];
                const float cosv = d / fmaxf(rn_s[r] * qn, EPS_);
                float dd = rsc_s[r] - qsc; dd *= dd;
                const float sim   = cosv * (1.f - dd);
                const bool  sel   = (cosv >= THR_);
                const float sim_m = sel ? sim : -1.f;
                const bool  valid = (rg < NCOL_);
                mn = fminf(mn, valid ? sim_m : INFINITY);
                mx = fmaxf(mx, valid ? sim_m : -INFINITY);
                sss += sim_m + 1.f;                 // OOB rows: cos=0 -> exactly 0
                ssl += (sim_m + 1.f) * lab_s[r];
                if (sel) { s0 += sim; cnt += 1.f; }
            }
        }
        mn  = fminf(mn, __shfl_xor(mn, 16)); mn  = fminf(mn, __shfl_xor(mn, 32));
        mx  = fmaxf(mx, __shfl_xor(mx, 16)); mx  = fmaxf(mx, __shfl_xor(mx, 32));
        sss += __shfl_xor(sss, 16); sss += __shfl_xor(sss, 32);
        ssl += __shfl_xor(ssl, 16); ssl += __shfl_xor(ssl, 32);
        s0  += __shfl_xor(s0, 16);  s0  += __shfl_xor(s0, 32);
        cnt += __shfl_xor(cnt, 16); cnt += __shfl_xor(cnt, 32);
        if (fq == 0) {
            atomicMinF(&qmn[c], mn);
            atomicMaxF(&qmx[c], mx);
            atomicAdd(&qss[c],  sss);
            atomicAdd(&qssl[c], ssl);
            atomicAdd(&qs0[c],  s0);
            atomicAdd(&qcnt[c], cnt);
        }
    }
    __syncthreads();
    if (t < NQ_) {
        atomicMinF(ws + WS_MN + t, qmn[t]);
        atomicMaxF(ws + WS_MX + t, qmx[t]);
        atomicAdd(ws + WS_SS + t,  qss[t]);
        atomicAdd(ws + WS_SSL + t, qssl[t]);
        atomicAdd(ws + WS_S0 + t,  qs0[t]);
        atomicAdd(ws + WS_CNT + t, qcnt[t]);
    }
}

// ---------------- kernel 3: finalize outputs ----------------
__global__ void lpe_final(float* out, const float* ws) {
    int t = threadIdx.x;
    if (t < BS_) {
        out[t] = 1.f;            // exp_itm_label[:64]
        out[192 + t] = 1.f;      // exp_wo_alter_label[:64]
        out[385 + t] = 0.f;      // weights[:64]
    }
    if (t == 0) out[384] = 1.0f; // gamma = 131264/131264
    if (t >= BS_ && t < NVL_) {
        int i = t - BS_;
        float mn   = ws[WS_MN + i],  mx   = ws[WS_MX + i];
        float ssP  = ws[WS_SS + i],  sslP = ws[WS_SSL + i];
        float s0   = ws[WS_S0 + i],  cnt  = ws[WS_CNT + i];
        float Sl   = ws[WS_SL];
        float denomA = mx - mn + 1e-8f;
        float shift  = mn + 1.f;            // == 0 when min is the -1 sentinel
        float sumd = (ssP - (float)NCOL_ * shift) / denomA;
        float num  = (sslP - shift * Sl) / denomA;
        float wo   = num / (sumd + 1e-8f);
        float alt  = fmaxf(wo, 0.f);
        float w    = (cnt != 0.f) ? s0 / fmaxf(cnt, 1.f) : 0.f;
        float wt   = fmaxf(w - THR_, 0.f) / (1.f - THR_);
        out[BS_ + i] = alt;          // exp_itm_label[64:]
        out[192 + BS_ + i] = wo;     // exp_wo_alter_label[64:]
        out[385 + BS_ + i] = wt;     // weights[64:]
    }
}

extern "C" void kernel_launch(void* const* d_in, const int* in_sizes, int n_in,
                              void* d_out, int out_size, void* d_ws, size_t ws_size,
                              hipStream_t stream) {
    const float* vl    = (const float*)d_in[0];
    const float* score = (const float*)d_in[1];
    const float* itm   = (const float*)d_in[2];
    const float* queue = (const float*)d_in[3];
    const float* expl  = (const float*)d_in[4];
    const float* W     = (const float*)d_in[5];
    const float* b     = (const float*)d_in[6];
    float* out = (float*)d_out;
    float* ws  = (float*)d_ws;

    lpe_init<<<1, 256, 0, stream>>>(ws);
    lpe_prep<<<NQ_ + 256, 256, 0, stream>>>(vl, itm, expl, ws);
    const int nblk = (NCOL_ + TM - 1) / TM;   // 1026
    lpe_main<<<nblk, 256, 0, stream>>>(vl, score, itm, queue, expl, W, b, ws);
    lpe_final<<<1, 256, 0, stream>>>(out, ws);
}